// Round 3
// baseline (534.037 us; speedup 1.0000x reference)
//
#include <hip/hip_runtime.h>
#include <hip/hip_bf16.h>

// FeatureInspector: ska (dynamic 3x3 per-group aggregation) -> *roi ->
// grouped conv3x3(G=8)+BN+ReLU -> conv1x1+BN -> out = ska + y
//
// R5: ska grid XCD-chunk swizzled (virt = (phys&7)*4096 + phys>>3) so each
//     XCD owns one batch b and sweeps (g,h) sequentially -> h+-1 halo rows
//     hit the same XCD's L2 (R4 had even/odd h on different XCDs -> 2.3x
//     x over-fetch, FETCH 346MB). Prepacks merged into one launch.
//  ska: block = 32ci x 32w of one (b,g,h) row; dw/roi wave-broadcast;
//       y0b bf16 channel-last via 2KB LDS transpose.
//  conv1: implicit GEMM, 9 shifted K=32 MFMAs; LDS x-tile [px 18x18][ci32
//         pad40] bf16; B-frags in registers from L2; LDS-transposed epilogue.
//  conv2: register GEMM M=64px/block, N=256, K=256; frags from global.
//
// ws layout (bytes):
//   [0, 67108864)          y0b bf16 ska*roi, channel-last [b][g][hw][ci32]
//   [67108864, +67108864)  h1t bf16 [b][g][hw][ci32]
//   [134217728, +147456)   w1b bf16 [g][khw][co][ci32]
//   [134365184, +131072)   w2b bf16 [co][ci256]

#define HW 16384
#define EPS 1e-5f

typedef __bf16 bf16x8 __attribute__((ext_vector_type(8)));
typedef short short8 __attribute__((ext_vector_type(8)));
typedef short short4v __attribute__((ext_vector_type(4)));
typedef float floatx4 __attribute__((ext_vector_type(4)));

__device__ __forceinline__ unsigned short f2bf(float f) {
  unsigned u = __builtin_bit_cast(unsigned, f);
  unsigned r = u + 0x7FFFu + ((u >> 16) & 1u);
  return (unsigned short)(r >> 16);
}

__device__ __forceinline__ floatx4 mfma16(short8 a, short8 b, floatx4 c) {
  return __builtin_amdgcn_mfma_f32_16x16x32_bf16(
      __builtin_bit_cast(bf16x8, a), __builtin_bit_cast(bf16x8, b), c, 0, 0, 0);
}

// w1b: [g][khw][co][ci32] (73728 elems) ; w2b: [co][ci256] (65536 elems)
__global__ __launch_bounds__(256) void prepack(const float* __restrict__ w1,
                                               const float* __restrict__ w2,
                                               unsigned short* __restrict__ w1b,
                                               unsigned short* __restrict__ w2b) {
  int o = blockIdx.x * 256 + threadIdx.x;      // 544 blocks = 139264
  if (o < 73728) {
    int ci  = o & 31;
    int co  = (o >> 5) & 31;
    int khw = (o >> 10) % 9;
    int g   = (o >> 10) / 9;
    w1b[o] = f2bf(w1[((g * 32 + co) * 32 + ci) * 9 + khw]);
  } else {
    int p = o - 73728;
    w2b[p] = f2bf(w2[p]);
  }
}

// Block = one (b,g,h) row, 32ci x 32w tile. Thread: ci = tid>>3, 4 w's.
// dw/roi loads identical across the 8-lane ci groups -> L1 broadcast.
// out (fp32 planar) direct; y0b (bf16 channel-last) via LDS transpose.
// Grid XCD-chunked: XCD k processes virt [k*4096,(k+1)*4096) = batch k.
__global__ __launch_bounds__(256) void ska_kernel(const float* __restrict__ x,
                                                  const float* __restrict__ dw,
                                                  const float* __restrict__ roi,
                                                  float* __restrict__ out,
                                                  unsigned short* __restrict__ y0b) {
  __shared__ unsigned short tile[32 * 36];     // [w32][ci stride36]

  int phys = blockIdx.x;                       // 32768
  int blk  = (phys & 7) * 4096 + (phys >> 3);  // bijective (32768 % 8 == 0)
  int wt = blk & 3;
  int h  = (blk >> 2) & 127;
  int g  = (blk >> 9) & 7;
  int b  = blk >> 12;
  int tid = threadIdx.x;
  int ci = tid >> 3;
  int wq = tid & 7;
  int w0 = wt * 32 + wq * 4;
  int c  = g * 32 + ci;

  size_t base = ((size_t)(b * 256 + c)) * HW + h * 128 + w0;
  const float* dwb = dw + ((size_t)(b * 8 + g) * 9) * HW + h * 128 + w0;

  floatx4 wv[9];
#pragma unroll
  for (int k = 0; k < 9; ++k) wv[k] = *(const floatx4*)&dwb[k * HW];

  float xr[3][6];
#pragma unroll
  for (int kh = 0; kh < 3; ++kh) {
    int hh = h + kh - 1;
    if ((unsigned)hh < 128u) {
      const float* xp = x + base + (kh - 1) * 128;
      floatx4 m = *(const floatx4*)xp;
      xr[kh][0] = (w0 > 0) ? xp[-1] : 0.f;
      xr[kh][1] = m[0];
      xr[kh][2] = m[1];
      xr[kh][3] = m[2];
      xr[kh][4] = m[3];
      xr[kh][5] = (w0 < 124) ? xp[4] : 0.f;
    } else {
#pragma unroll
      for (int i = 0; i < 6; ++i) xr[kh][i] = 0.f;
    }
  }

  floatx4 rv = *(const floatx4*)&roi[(size_t)b * HW + h * 128 + w0];

  float s[4] = {0.f, 0.f, 0.f, 0.f};
#pragma unroll
  for (int kh = 0; kh < 3; ++kh) {
#pragma unroll
    for (int kw = 0; kw < 3; ++kw) {
      floatx4 wk = wv[kh * 3 + kw];
#pragma unroll
      for (int j = 0; j < 4; ++j) s[j] += xr[kh][kw + j] * wk[j];
    }
  }

  *(floatx4*)&out[base] = (floatx4){s[0], s[1], s[2], s[3]};

  int wl = wq * 4;
#pragma unroll
  for (int j = 0; j < 4; ++j)
    tile[(wl + j) * 36 + ci] = f2bf(s[j] * rv[j]);

  __syncthreads();

  // cooperative coalesced store: 1024 u16 = 2KB contiguous
  unsigned short* dst =
      y0b + ((size_t)(b * 8 + g) * HW + h * 128 + wt * 32) * 32;
  int w = tid >> 3, k = tid & 7;
  *(short4v*)&dst[tid * 4] = *(const short4v*)&tile[w * 36 + k * 4];
}

// Grouped conv3x3 + BN1 + ReLU via MFMA.
// Block: 16x16 px tile of one (b,g); 4 waves; wave = 4 rows x 32 co.
// LDS: x-tile [18*18 px][ci stride 40] bf16 = 25920 B (reused for epilogue).
__global__ __launch_bounds__(256) void conv1_mfma(
    const unsigned short* __restrict__ y0, const unsigned short* __restrict__ w1b,
    const float* __restrict__ g1, const float* __restrict__ b1,
    const float* __restrict__ m1, const float* __restrict__ v1,
    unsigned short* __restrict__ h1t) {
  __shared__ unsigned short xt[324 * 40];

  int blk  = blockIdx.x;              // 4096 = 8b * 8g * 64 tiles
  int tile = blk & 63;
  int g    = (blk >> 6) & 7;
  int b    = blk >> 9;
  int h0   = (tile >> 3) * 16;
  int w0   = (tile & 7) * 16;
  int tid  = threadIdx.x;

  // staging: y0 is [px][ci32] -> 64B contiguous per px; 16B vec per task
  const unsigned short* xsrc = y0 + (size_t)(b * 8 + g) * HW * 32;
  for (int j = tid; j < 1296; j += 256) {     // 324 px * 4 parts
    int r = j >> 2, part = j & 3;
    int yy = r / 18, xx = r - yy * 18;
    int gh = h0 - 1 + yy, gw = w0 - 1 + xx;
    short8 v = (short8){0, 0, 0, 0, 0, 0, 0, 0};
    if ((unsigned)gh < 128u && (unsigned)gw < 128u)
      v = *(const short8*)&xsrc[(size_t)(gh * 128 + gw) * 32 + part * 8];
    *(short8*)&xt[r * 40 + part * 8] = v;
  }

  int wv = tid >> 6, lane = tid & 63, q = lane >> 4, n = lane & 15;

  // B-frags from global (L2-resident, 18 KB/group): [g][khw][co][ci32]
  short8 bf[9][2];
  const unsigned short* wgb = w1b + (size_t)g * 9 * 32 * 32;
#pragma unroll
  for (int khw = 0; khw < 9; ++khw) {
#pragma unroll
    for (int half = 0; half < 2; ++half)
      bf[khw][half] =
          *(const short8*)&wgb[(khw * 32 + half * 16 + n) * 32 + q * 8];
  }

  __syncthreads();

  floatx4 acc[4][2];
#pragma unroll
  for (int r = 0; r < 4; ++r)
#pragma unroll
    for (int half = 0; half < 2; ++half) acc[r][half] = (floatx4){0.f, 0.f, 0.f, 0.f};

#pragma unroll
  for (int r = 0; r < 4; ++r) {
    int row = wv * 4 + r;
#pragma unroll
    for (int khw = 0; khw < 9; ++khw) {
      int kh = khw / 3, kw = khw % 3;
      short8 a = *(const short8*)&xt[((row + kh) * 18 + kw + n) * 40 + q * 8];
      acc[r][0] = mfma16(a, bf[khw][0], acc[r][0]);
      acc[r][1] = mfma16(a, bf[khw][1], acc[r][1]);
    }
  }

  float inv[2], bias[2];
#pragma unroll
  for (int half = 0; half < 2; ++half) {
    int c = g * 32 + half * 16 + n;
    inv[half]  = g1[c] * rsqrtf(v1[c] + EPS);
    bias[half] = b1[c] - m1[c] * inv[half];
  }

  __syncthreads();                     // xt reads done; reuse as [px256][co40]

#pragma unroll
  for (int r = 0; r < 4; ++r) {
    int pr = (wv * 4 + r) * 16;
#pragma unroll
    for (int half = 0; half < 2; ++half) {
      int co = half * 16 + n;
#pragma unroll
      for (int reg = 0; reg < 4; ++reg) {
        int px = pr + q * 4 + reg;
        float v = fmaxf(acc[r][half][reg] * inv[half] + bias[half], 0.f);
        xt[px * 40 + co] = f2bf(v);
      }
    }
  }

  __syncthreads();

  // coalesced h1t store: thread = one px (16x16 tile), 4x16B
  unsigned short* hb = h1t + (size_t)(b * 8 + g) * HW * 32;
  int ph = tid >> 4, pw = tid & 15;
  size_t gp = (size_t)((h0 + ph) * 128 + (w0 + pw)) * 32;
#pragma unroll
  for (int k = 0; k < 4; ++k)
    *(short8*)&hb[gp + k * 8] = *(const short8*)&xt[tid * 40 + k * 8];
}

// 1x1 conv + BN2 + residual. Register GEMM: block = 64 px x 256 co of one b;
// wave = 64 px x 64 co. K = 256 (8 slabs of 32 = one group each). No LDS.
__global__ __launch_bounds__(256) void conv2_mfma(
    const unsigned short* __restrict__ h1t, const unsigned short* __restrict__ w2b,
    const float* __restrict__ g2, const float* __restrict__ b2,
    const float* __restrict__ m2, const float* __restrict__ v2,
    float* __restrict__ out) {
  int blk = blockIdx.x;               // 2048 = 8b * 256 px-tiles
  int b   = blk >> 8;
  int px0 = (blk & 255) * 64;
  int tid = threadIdx.x;
  int wv = tid >> 6, lane = tid & 63, q = lane >> 4, n = lane & 15;

  floatx4 acc[4][4];                  // [mt][nt]
#pragma unroll
  for (int mt = 0; mt < 4; ++mt)
#pragma unroll
    for (int nt = 0; nt < 4; ++nt) acc[mt][nt] = (floatx4){0.f, 0.f, 0.f, 0.f};

  for (int s = 0; s < 8; ++s) {       // K-slab = group s
    short8 a[4];
#pragma unroll
    for (int mt = 0; mt < 4; ++mt)
      a[mt] = *(const short8*)&h1t[((size_t)(b * 8 + s) * HW + px0 + mt * 16 + n) * 32 +
                                   q * 8];
#pragma unroll
    for (int nt = 0; nt < 4; ++nt) {
      int co = wv * 64 + nt * 16 + n;
      short8 bb = *(const short8*)&w2b[co * 256 + s * 32 + q * 8];
#pragma unroll
      for (int mt = 0; mt < 4; ++mt) acc[mt][nt] = mfma16(a[mt], bb, acc[mt][nt]);
    }
  }

#pragma unroll
  for (int nt = 0; nt < 4; ++nt) {
    int co = wv * 64 + nt * 16 + n;
    float inv  = g2[co] * rsqrtf(v2[co] + EPS);
    float bias = b2[co] - m2[co] * inv;
    float* ob = out + (size_t)(b * 256 + co) * HW;
#pragma unroll
    for (int mt = 0; mt < 4; ++mt) {
      int px = px0 + mt * 16 + q * 4;
      float4 sv = *(float4*)&ob[px];
      sv.x += acc[mt][nt][0] * inv + bias;
      sv.y += acc[mt][nt][1] * inv + bias;
      sv.z += acc[mt][nt][2] * inv + bias;
      sv.w += acc[mt][nt][3] * inv + bias;
      *(float4*)&ob[px] = sv;
    }
  }
}

extern "C" void kernel_launch(void* const* d_in, const int* in_sizes, int n_in,
                              void* d_out, int out_size, void* d_ws,
                              size_t ws_size, hipStream_t stream) {
  const float* x   = (const float*)d_in[0];
  const float* dw  = (const float*)d_in[1];
  const float* roi = (const float*)d_in[2];
  const float* w1  = (const float*)d_in[3];
  const float* g1  = (const float*)d_in[4];
  const float* b1  = (const float*)d_in[5];
  const float* m1  = (const float*)d_in[6];
  const float* v1  = (const float*)d_in[7];
  const float* w2  = (const float*)d_in[8];
  const float* g2  = (const float*)d_in[9];
  const float* b2  = (const float*)d_in[10];
  const float* m2  = (const float*)d_in[11];
  const float* v2  = (const float*)d_in[12];
  float* out = (float*)d_out;

  char* ws = (char*)d_ws;
  unsigned short* y0b = (unsigned short*)ws;                 // 67108864 B
  unsigned short* h1t = (unsigned short*)(ws + 67108864);    // 67108864 B
  unsigned short* w1b = (unsigned short*)(ws + 134217728);   // 147456 B
  unsigned short* w2b = (unsigned short*)(ws + 134365184);   // 131072 B

  prepack<<<544, 256, 0, stream>>>(w1, w2, w1b, w2b);
  ska_kernel<<<32768, 256, 0, stream>>>(x, dw, roi, out, y0b);
  conv1_mfma<<<4096, 256, 0, stream>>>(y0b, w1b, g1, b1, m1, v1, h1t);
  conv2_mfma<<<2048, 256, 0, stream>>>(h1t, w2b, g2, b2, m2, v2, out);
}

// Round 4
// 459.778 us; speedup vs baseline: 1.1615x; 1.1615x over previous
//
#include <hip/hip_runtime.h>
#include <hip/hip_bf16.h>

// FeatureInspector: ska (dynamic 3x3 per-group aggregation) -> *roi ->
// grouped conv3x3(G=8)+BN+ReLU -> conv1x1+BN -> out = ska + y
//
// R6: attack memory-latency serialization (R5 evidence: time ~const across
//     3x traffic change, VGPR=36 -> compiler serialized loads).
//  ska: 2 rows/thread; dw+roi staged cooperatively in LDS (broadcast
//       ds_read_b128 at use); x window loads batched pre-sync;
//       __launch_bounds__(256,4) for VGPR headroom (128 cap).
//  conv1: staging loads batched into regs (1 latency wait, not 6).
//  conv2: A-slabs via global_load_lds into 3-buffer LDS pipeline,
//         depth-2 prefetch, counted vmcnt(1) (T3-minimum recipe).
//
// ws layout (bytes):
//   [0, 67108864)          y0b bf16 ska*roi, channel-last [b][g][hw][ci32]
//   [67108864, +67108864)  h1t bf16 [b][g][hw][ci32]
//   [134217728, +147456)   w1b bf16 [g][khw][co][ci32]
//   [134365184, +131072)   w2b bf16 [co][ci256]

#define HW 16384
#define EPS 1e-5f

typedef __bf16 bf16x8 __attribute__((ext_vector_type(8)));
typedef short short8 __attribute__((ext_vector_type(8)));
typedef short short4v __attribute__((ext_vector_type(4)));
typedef float floatx4 __attribute__((ext_vector_type(4)));

__device__ __forceinline__ unsigned short f2bf(float f) {
  unsigned u = __builtin_bit_cast(unsigned, f);
  unsigned r = u + 0x7FFFu + ((u >> 16) & 1u);
  return (unsigned short)(r >> 16);
}

__device__ __forceinline__ floatx4 mfma16(short8 a, short8 b, floatx4 c) {
  return __builtin_amdgcn_mfma_f32_16x16x32_bf16(
      __builtin_bit_cast(bf16x8, a), __builtin_bit_cast(bf16x8, b), c, 0, 0, 0);
}

// w1b: [g][khw][co][ci32] (73728 elems) ; w2b: [co][ci256] (65536 elems)
__global__ __launch_bounds__(256) void prepack(const float* __restrict__ w1,
                                               const float* __restrict__ w2,
                                               unsigned short* __restrict__ w1b,
                                               unsigned short* __restrict__ w2b) {
  int o = blockIdx.x * 256 + threadIdx.x;      // 544 blocks = 139264
  if (o < 73728) {
    int ci  = o & 31;
    int co  = (o >> 5) & 31;
    int khw = (o >> 10) % 9;
    int g   = (o >> 10) / 9;
    w1b[o] = f2bf(w1[((g * 32 + co) * 32 + ci) * 9 + khw]);
  } else {
    int p = o - 73728;
    w2b[p] = f2bf(w2[p]);
  }
}

// Block = one (b,g,hpair,wt): 2 rows x 32 w x 32 ci. Thread: ci=tid>>3,
// wq=tid&7 -> 2x4 outputs. dw/roi cooperatively staged in LDS (read back
// as wq-indexed broadcast b128). x window (4 rows x 6 cols) batched loads.
// Grid XCD-chunked: XCD k owns batch k (2048 consecutive virt blocks).
__global__ __launch_bounds__(256, 4) void ska_kernel(
    const float* __restrict__ x, const float* __restrict__ dw,
    const float* __restrict__ roi, float* __restrict__ out,
    unsigned short* __restrict__ y0b) {
  __shared__ float dwf[9][2][32];
  __shared__ float roib[2][32];
  __shared__ unsigned short tile[2 * 32 * 36];

  int phys = blockIdx.x;                       // 16384
  int blk  = (phys & 7) * 2048 + (phys >> 3);  // bijective (16384 % 8 == 0)
  int wt = blk & 3;
  int hp = (blk >> 2) & 63;
  int g  = (blk >> 8) & 7;
  int b  = blk >> 11;
  int h0 = hp * 2;
  int tid = threadIdx.x;
  int ci = tid >> 3;
  int wq = tid & 7;
  int w0 = wt * 32 + wq * 4;
  int c  = g * 32 + ci;

  // cooperative dw/roi stage: 144 + 16 threads, one dwordx4 each
  if (tid < 160) {
    if (tid < 144) {
      int k = tid >> 4, r = (tid >> 3) & 1, w4 = (tid & 7) * 4;
      *(floatx4*)&dwf[k][r][w4] = *(const floatx4*)
          &dw[((size_t)(b * 8 + g) * 9 + k) * HW + (h0 + r) * 128 + wt * 32 + w4];
    } else {
      int i = tid - 144, r = i >> 3, w4 = (i & 7) * 4;
      *(floatx4*)&roib[r][w4] = *(const floatx4*)
          &roi[(size_t)b * HW + (h0 + r) * 128 + wt * 32 + w4];
    }
  }

  // per-thread x window: rows h0-1..h0+2, cols w0-1..w0+4 (all independent)
  float xr[4][6];
#pragma unroll
  for (int rr = 0; rr < 4; ++rr) {
    int hh = h0 - 1 + rr;
    if ((unsigned)hh < 128u) {
      const float* xp = &x[((size_t)(b * 256 + c)) * HW + hh * 128 + w0];
      floatx4 m = *(const floatx4*)xp;
      xr[rr][0] = (w0 > 0) ? xp[-1] : 0.f;
      xr[rr][1] = m[0];
      xr[rr][2] = m[1];
      xr[rr][3] = m[2];
      xr[rr][4] = m[3];
      xr[rr][5] = (w0 < 124) ? xp[4] : 0.f;
    } else {
#pragma unroll
      for (int i = 0; i < 6; ++i) xr[rr][i] = 0.f;
    }
  }

  __syncthreads();

  size_t base = ((size_t)(b * 256 + c)) * HW + h0 * 128 + w0;
#pragma unroll
  for (int r = 0; r < 2; ++r) {
    float s[4] = {0.f, 0.f, 0.f, 0.f};
#pragma unroll
    for (int kh = 0; kh < 3; ++kh)
#pragma unroll
      for (int kw = 0; kw < 3; ++kw) {
        floatx4 wk = *(const floatx4*)&dwf[kh * 3 + kw][r][wq * 4];
#pragma unroll
        for (int j = 0; j < 4; ++j) s[j] += xr[r + kh][kw + j] * wk[j];
      }
    *(floatx4*)&out[base + r * 128] = (floatx4){s[0], s[1], s[2], s[3]};
    floatx4 rv = *(const floatx4*)&roib[r][wq * 4];
#pragma unroll
    for (int j = 0; j < 4; ++j)
      tile[(r * 32 + wq * 4 + j) * 36 + ci] = f2bf(s[j] * rv[j]);
  }

  __syncthreads();

  // cooperative coalesced y0b store: 2 rows x 2KB contiguous
  unsigned short* dst =
      y0b + ((size_t)(b * 8 + g) * HW + h0 * 128 + wt * 32) * 32;
  int row = tid >> 7, rest = tid & 127;
  int w = rest >> 2, kk = rest & 3;
  *(short8*)&dst[(size_t)row * 128 * 32 + w * 32 + kk * 8] =
      *(const short8*)&tile[(row * 32 + w) * 36 + kk * 8];
}

// Grouped conv3x3 + BN1 + ReLU via MFMA.
// Block: 16x16 px tile of one (b,g); 4 waves; wave = 4 rows x 32 co.
// LDS: x-tile [18*18 px][ci stride 40] bf16 = 25920 B (reused for epilogue).
__global__ __launch_bounds__(256) void conv1_mfma(
    const unsigned short* __restrict__ y0, const unsigned short* __restrict__ w1b,
    const float* __restrict__ g1, const float* __restrict__ b1,
    const float* __restrict__ m1, const float* __restrict__ v1,
    unsigned short* __restrict__ h1t) {
  __shared__ unsigned short xt[324 * 40];

  int blk  = blockIdx.x;              // 4096 = 8b * 8g * 64 tiles
  int tile = blk & 63;
  int g    = (blk >> 6) & 7;
  int b    = blk >> 9;
  int h0   = (tile >> 3) * 16;
  int w0   = (tile & 7) * 16;
  int tid  = threadIdx.x;

  // staging: batch all 6 global loads into regs first (one latency wait),
  // then ds_write. y0 is [px][ci32] -> 16B vec per task.
  const unsigned short* xsrc = y0 + (size_t)(b * 8 + g) * HW * 32;
  short8 sv[6];
#pragma unroll
  for (int t = 0; t < 6; ++t) {
    int j = tid + t * 256;
    short8 v = (short8){0, 0, 0, 0, 0, 0, 0, 0};
    if (j < 1296) {
      int r = j >> 2, part = j & 3;
      int yy = r / 18, xx = r - yy * 18;
      int gh = h0 - 1 + yy, gw = w0 - 1 + xx;
      if ((unsigned)gh < 128u && (unsigned)gw < 128u)
        v = *(const short8*)&xsrc[(size_t)(gh * 128 + gw) * 32 + part * 8];
    }
    sv[t] = v;
  }
#pragma unroll
  for (int t = 0; t < 6; ++t) {
    int j = tid + t * 256;
    if (j < 1296) {
      int r = j >> 2, part = j & 3;
      *(short8*)&xt[r * 40 + part * 8] = sv[t];
    }
  }

  int wv = tid >> 6, lane = tid & 63, q = lane >> 4, n = lane & 15;

  // B-frags from global (L2-resident, 18 KB/group): [g][khw][co][ci32]
  short8 bf[9][2];
  const unsigned short* wgb = w1b + (size_t)g * 9 * 32 * 32;
#pragma unroll
  for (int khw = 0; khw < 9; ++khw) {
#pragma unroll
    for (int half = 0; half < 2; ++half)
      bf[khw][half] =
          *(const short8*)&wgb[(khw * 32 + half * 16 + n) * 32 + q * 8];
  }

  __syncthreads();

  floatx4 acc[4][2];
#pragma unroll
  for (int r = 0; r < 4; ++r)
#pragma unroll
    for (int half = 0; half < 2; ++half) acc[r][half] = (floatx4){0.f, 0.f, 0.f, 0.f};

#pragma unroll
  for (int r = 0; r < 4; ++r) {
    int row = wv * 4 + r;
#pragma unroll
    for (int khw = 0; khw < 9; ++khw) {
      int kh = khw / 3, kw = khw % 3;
      short8 a = *(const short8*)&xt[((row + kh) * 18 + kw + n) * 40 + q * 8];
      acc[r][0] = mfma16(a, bf[khw][0], acc[r][0]);
      acc[r][1] = mfma16(a, bf[khw][1], acc[r][1]);
    }
  }

  float inv[2], bias[2];
#pragma unroll
  for (int half = 0; half < 2; ++half) {
    int cc = g * 32 + half * 16 + n;
    inv[half]  = g1[cc] * rsqrtf(v1[cc] + EPS);
    bias[half] = b1[cc] - m1[cc] * inv[half];
  }

  __syncthreads();                     // xt reads done; reuse as [px256][co40]

#pragma unroll
  for (int r = 0; r < 4; ++r) {
    int pr = (wv * 4 + r) * 16;
#pragma unroll
    for (int half = 0; half < 2; ++half) {
      int co = half * 16 + n;
#pragma unroll
      for (int reg = 0; reg < 4; ++reg) {
        int px = pr + q * 4 + reg;
        float v = fmaxf(acc[r][half][reg] * inv[half] + bias[half], 0.f);
        xt[px * 40 + co] = f2bf(v);
      }
    }
  }

  __syncthreads();

  // coalesced h1t store: thread = one px (16x16 tile), 4x16B
  unsigned short* hb = h1t + (size_t)(b * 8 + g) * HW * 32;
  int ph = tid >> 4, pw = tid & 15;
  size_t gp = (size_t)((h0 + ph) * 128 + (w0 + pw)) * 32;
#pragma unroll
  for (int k = 0; k < 4; ++k)
    *(short8*)&hb[gp + k * 8] = *(const short8*)&xt[tid * 40 + k * 8];
}

// 1x1 conv + BN2 + residual. Register GEMM: block = 64 px x 256 co of one b;
// wave = 64 px x 64 co. K = 256 (8 slabs of 32 = one group each).
// A-slabs (4KB contiguous) staged via global_load_lds, 3-buffer pipeline,
// depth-2 prefetch with counted vmcnt (T3-minimum). B frags from L2.
__global__ __launch_bounds__(256) void conv2_mfma(
    const unsigned short* __restrict__ h1t, const unsigned short* __restrict__ w2b,
    const float* __restrict__ g2, const float* __restrict__ b2,
    const float* __restrict__ m2, const float* __restrict__ v2,
    float* __restrict__ out) {
  __shared__ unsigned short As[3][2048];    // 3 x 4KB slabs

  int blk = blockIdx.x;               // 2048 = 8b * 256 px-tiles
  int b   = blk >> 8;
  int px0 = (blk & 255) * 64;
  int tid = threadIdx.x;
  int wv = tid >> 6, lane = tid & 63, q = lane >> 4, n = lane & 15;

  const unsigned short* sb = h1t + ((size_t)b * 8 * HW + px0) * 32;

  // wave wv stages its 1KB quarter: per-lane global src, wave-uniform LDS dst
#define STAGE(S, BUF)                                                         \
  __builtin_amdgcn_global_load_lds(                                           \
      (const __attribute__((address_space(1))) unsigned int*)(sb +            \
          (size_t)(S) * HW * 32 + wv * 512 + lane * 8),                       \
      (__attribute__((address_space(3))) unsigned int*)&As[BUF][wv * 512],    \
      16, 0, 0)

  floatx4 acc[4][4];                  // [mt][nt]
#pragma unroll
  for (int mt = 0; mt < 4; ++mt)
#pragma unroll
    for (int nt = 0; nt < 4; ++nt) acc[mt][nt] = (floatx4){0.f, 0.f, 0.f, 0.f};

  STAGE(0, 0);
  STAGE(1, 1);
  asm volatile("s_waitcnt vmcnt(1)");  // slab 0 resident (1 stage may remain)
  __syncthreads();

#pragma unroll
  for (int s = 0; s < 8; ++s) {       // K-slab = group s
    if (s < 6) STAGE(s + 2, (s + 2) % 3);
    short8 bb[4];
#pragma unroll
    for (int nt = 0; nt < 4; ++nt)
      bb[nt] =
          *(const short8*)&w2b[(wv * 64 + nt * 16 + n) * 256 + s * 32 + q * 8];
    const unsigned short* Ab = &As[s % 3][0];
#pragma unroll
    for (int mt = 0; mt < 4; ++mt) {
      short8 a = *(const short8*)&Ab[(mt * 16 + n) * 32 + q * 8];
#pragma unroll
      for (int nt = 0; nt < 4; ++nt) acc[mt][nt] = mfma16(a, bb[nt], acc[mt][nt]);
    }
    if (s < 6) asm volatile("s_waitcnt vmcnt(1)");       // slab s+1 resident
    else if (s == 6) asm volatile("s_waitcnt vmcnt(0)"); // slab 7 resident
    if (s < 7) __syncthreads();
  }
#undef STAGE

#pragma unroll
  for (int nt = 0; nt < 4; ++nt) {
    int co = wv * 64 + nt * 16 + n;
    float inv  = g2[co] * rsqrtf(v2[co] + EPS);
    float bias = b2[co] - m2[co] * inv;
    float* ob = out + (size_t)(b * 256 + co) * HW;
#pragma unroll
    for (int mt = 0; mt < 4; ++mt) {
      int px = px0 + mt * 16 + q * 4;
      float4 sv = *(float4*)&ob[px];
      sv.x += acc[mt][nt][0] * inv + bias;
      sv.y += acc[mt][nt][1] * inv + bias;
      sv.z += acc[mt][nt][2] * inv + bias;
      sv.w += acc[mt][nt][3] * inv + bias;
      *(float4*)&ob[px] = sv;
    }
  }
}

extern "C" void kernel_launch(void* const* d_in, const int* in_sizes, int n_in,
                              void* d_out, int out_size, void* d_ws,
                              size_t ws_size, hipStream_t stream) {
  const float* x   = (const float*)d_in[0];
  const float* dw  = (const float*)d_in[1];
  const float* roi = (const float*)d_in[2];
  const float* w1  = (const float*)d_in[3];
  const float* g1  = (const float*)d_in[4];
  const float* b1  = (const float*)d_in[5];
  const float* m1  = (const float*)d_in[6];
  const float* v1  = (const float*)d_in[7];
  const float* w2  = (const float*)d_in[8];
  const float* g2  = (const float*)d_in[9];
  const float* b2  = (const float*)d_in[10];
  const float* m2  = (const float*)d_in[11];
  const float* v2  = (const float*)d_in[12];
  float* out = (float*)d_out;

  char* ws = (char*)d_ws;
  unsigned short* y0b = (unsigned short*)ws;                 // 67108864 B
  unsigned short* h1t = (unsigned short*)(ws + 67108864);    // 67108864 B
  unsigned short* w1b = (unsigned short*)(ws + 134217728);   // 147456 B
  unsigned short* w2b = (unsigned short*)(ws + 134365184);   // 131072 B

  prepack<<<544, 256, 0, stream>>>(w1, w2, w1b, w2b);
  ska_kernel<<<16384, 256, 0, stream>>>(x, dw, roi, out, y0b);
  conv1_mfma<<<4096, 256, 0, stream>>>(y0b, w1b, g1, b1, m1, v1, h1t);
  conv2_mfma<<<2048, 256, 0, stream>>>(h1t, w2b, g2, b2, m2, v2, out);
}